// Round 1
// baseline (1426.200 us; speedup 1.0000x reference)
//
#include <hip/hip_runtime.h>
#include <float.h>

#define D_DIM 768
#define BM 64
#define BN 512
#define BD 16
#define NTH 512

// ws layout:
//   [0, 2048)            : cnorm  float[512]
//   [4096, 4096+65536)   : partial double[16][512]

__global__ void cnorm_partial_kernel(const float* __restrict__ C,
                                     double* __restrict__ partial, int K) {
    const int k = threadIdx.x;   // 0..511
    const int w = blockIdx.x;    // 0..15
    double s = 0.0;
    if (k < K) {
        const int d0 = w * (D_DIM / 16);
        for (int d = d0; d < d0 + (D_DIM / 16); ++d) {
            const float c = C[(size_t)d * K + k];
            s = fma((double)c, (double)c, s);
        }
    }
    partial[w * 512 + k] = s;
}

__global__ void cnorm_finish_kernel(const double* __restrict__ partial,
                                    float* __restrict__ cnorm, int K) {
    const int k = threadIdx.x;   // 0..511
    if (k < K) {
        double s = 0.0;
        for (int w = 0; w < 16; ++w) s += partial[w * 512 + k];
        cnorm[k] = (float)s;
    } else {
        cnorm[k] = FLT_MAX;      // pad clusters never win
    }
}

__launch_bounds__(NTH, 4)
__global__ void assign_kernel(const float* __restrict__ feat,
                              const float* __restrict__ C,
                              const float* __restrict__ cnorm,
                              int* __restrict__ out,
                              int T, int K) {
    __shared__ __align__(16) float fs[BD][BM];   // feat tile, transposed: fs[dd][row]
    __shared__ __align__(16) float cs[BD][BN];   // C tile: cs[dd][col]

    const int tid = threadIdx.x;
    const int tc  = tid & 31;    // col-thread 0..31
    const int tr  = tid >> 5;    // row-thread 0..15
    const int R0  = blockIdx.x * BM;

    float acc[4][16];
    #pragma unroll
    for (int i = 0; i < 4; ++i)
        #pragma unroll
        for (int j = 0; j < 16; ++j) acc[i][j] = 0.0f;

    for (int d0 = 0; d0 < D_DIM; d0 += BD) {
        // ---- stage feat tile: 64 rows x 16 d, transposed into fs[dd][row]
        if (tid < 256) {
            const int row = tid >> 2;
            const int dp  = (tid & 3) << 2;
            float4 v = make_float4(0.f, 0.f, 0.f, 0.f);
            const int r = R0 + row;
            if (r < T) v = *(const float4*)(feat + (size_t)r * D_DIM + d0 + dp);
            fs[dp + 0][row] = v.x;
            fs[dp + 1][row] = v.y;
            fs[dp + 2][row] = v.z;
            fs[dp + 3][row] = v.w;
        }
        // ---- stage C tile: 16 d-rows x 512 cols (zeros in pad cols)
        {
            const int dd = tr;                       // 0..15
            const float* Crow = C + (size_t)(d0 + dd) * K;
            #pragma unroll
            for (int j = 0; j < 16; ++j) {
                const int k = tc + 32 * j;           // coalesced, conflict-free banks
                cs[dd][k] = (k < K) ? Crow[k] : 0.0f;
            }
        }
        __syncthreads();

        // ---- inner product accumulation
        #pragma unroll
        for (int dd = 0; dd < BD; ++dd) {
            const float4 f4 = *(const float4*)&fs[dd][tr << 2];
            const float fa[4] = {f4.x, f4.y, f4.z, f4.w};
            const float4 c0 = *(const float4*)&cs[dd][(tc << 2)];
            const float4 c1 = *(const float4*)&cs[dd][(tc << 2) + 128];
            const float4 c2 = *(const float4*)&cs[dd][(tc << 2) + 256];
            const float4 c3 = *(const float4*)&cs[dd][(tc << 2) + 384];
            const float cc[16] = {c0.x, c0.y, c0.z, c0.w,
                                  c1.x, c1.y, c1.z, c1.w,
                                  c2.x, c2.y, c2.z, c2.w,
                                  c3.x, c3.y, c3.z, c3.w};
            #pragma unroll
            for (int i = 0; i < 4; ++i)
                #pragma unroll
                for (int j = 0; j < 16; ++j)
                    acc[i][j] = fmaf(fa[i], cc[j], acc[i][j]);
        }
        __syncthreads();
    }

    // ---- epilogue: score = cnorm[col] - 2*dot; fused argmin
    float cn[16];
    #pragma unroll
    for (int g = 0; g < 4; ++g) {
        const float4 c = *(const float4*)(cnorm + (tc << 2) + 128 * g);
        cn[4 * g + 0] = c.x; cn[4 * g + 1] = c.y;
        cn[4 * g + 2] = c.z; cn[4 * g + 3] = c.w;
    }

    #pragma unroll
    for (int i = 0; i < 4; ++i) {
        float best = cn[0] - 2.0f * acc[i][0];
        int bidx = (tc << 2);
        #pragma unroll
        for (int g = 0; g < 4; ++g) {
            #pragma unroll
            for (int u = 0; u < 4; ++u) {
                if (g == 0 && u == 0) continue;
                const int col = (tc << 2) + 128 * g + u;
                const float s = cn[4 * g + u] - 2.0f * acc[i][4 * g + u];
                if (s < best || (s == best && col < bidx)) { best = s; bidx = col; }
            }
        }
        // reduce (value, index) across the 32-lane half-wave; ties -> lower index
        #pragma unroll
        for (int m = 1; m < 32; m <<= 1) {
            const float ov = __shfl_xor(best, m, 64);
            const int   oi = __shfl_xor(bidx, m, 64);
            if (ov < best || (ov == best && oi < bidx)) { best = ov; bidx = oi; }
        }
        if (tc == 0) {
            const int r = R0 + (tr << 2) + i;
            if (r < T) out[r] = bidx;
        }
    }
}

extern "C" void kernel_launch(void* const* d_in, const int* in_sizes, int n_in,
                              void* d_out, int out_size, void* d_ws, size_t ws_size,
                              hipStream_t stream) {
    const float* feat = (const float*)d_in[0];
    const float* C    = (const float*)d_in[1];
    int* out          = (int*)d_out;
    const int T = in_sizes[0] / D_DIM;   // 100000
    const int K = in_sizes[1] / D_DIM;   // 500

    float*  cnorm   = (float*)d_ws;
    double* partial = (double*)((char*)d_ws + 4096);

    hipLaunchKernelGGL(cnorm_partial_kernel, dim3(16), dim3(512), 0, stream,
                       C, partial, K);
    hipLaunchKernelGGL(cnorm_finish_kernel, dim3(1), dim3(512), 0, stream,
                       partial, cnorm, K);

    const int grid = (T + BM - 1) / BM;
    hipLaunchKernelGGL(assign_kernel, dim3(grid), dim3(NTH), 0, stream,
                       feat, C, cnorm, out, T, K);
}